// Round 1
// baseline (767.230 us; speedup 1.0000x reference)
//
#include <hip/hip_runtime.h>

typedef unsigned short u16;
typedef __attribute__((ext_vector_type(4))) float f32x4;
typedef __attribute__((ext_vector_type(8))) u16 u16x8;
typedef __attribute__((ext_vector_type(4))) u16 u16x4;
typedef __attribute__((ext_vector_type(8))) __bf16 bf16x8;

#define BB 8
#define CC 1024
#define HWSZ 4096
#define EPS 1e-3f

__device__ __forceinline__ u16 f2bf(float f) {
  union { float f; unsigned u; } v; v.f = f;
  unsigned r = v.u + 0x7FFFu + ((v.u >> 16) & 1u);
  return (u16)(r >> 16);
}
__device__ __forceinline__ float bf2f(u16 h) {
  union { unsigned u; float f; } v; v.u = ((unsigned)h) << 16;
  return v.f;
}
__device__ __forceinline__ float silu(float v) {
  return v / (1.0f + __expf(-v));
}
__device__ __forceinline__ void gload_lds16(const void* g, void* l) {
  __builtin_amdgcn_global_load_lds((const __attribute__((address_space(1))) void*)g,
                                   (__attribute__((address_space(3))) void*)l, 16, 0, 0);
}

// ---------------------------------------------------------------- prep
// Fold BN scale into weights; compute fused biases.
__global__ __launch_bounds__(256) void prep_kernel(
    const float* __restrict__ w1, const float* __restrict__ w2, const float* __restrict__ w3,
    const float* __restrict__ g1, const float* __restrict__ b1, const float* __restrict__ m1, const float* __restrict__ v1,
    const float* __restrict__ g2, const float* __restrict__ b2, const float* __restrict__ m2, const float* __restrict__ v2,
    const float* __restrict__ g3, const float* __restrict__ b3, const float* __restrict__ m3, const float* __restrict__ v3,
    u16* __restrict__ w1f, u16* __restrict__ w3f, float* __restrict__ w2f,
    float* __restrict__ bs1, float* __restrict__ bs2, float* __restrict__ bs3)
{
  int tid = blockIdx.x * 256 + threadIdx.x;
  int stride = gridDim.x * 256;
  for (int i = tid; i < 1048576; i += stride) {
    int co = i >> 10;
    float s1 = g1[co] * rsqrtf(v1[co] + EPS);
    float s3 = g3[co] * rsqrtf(v3[co] + EPS);
    w1f[i] = f2bf(w1[i] * s1);
    w3f[i] = f2bf(w3[i] * s3);
  }
  if (tid < 9216) {
    int c = tid / 9;
    float s2 = g2[c] * rsqrtf(v2[c] + EPS);
    w2f[tid] = w2[tid] * s2;
  }
  if (tid < 1024) {
    float s1 = g1[tid] * rsqrtf(v1[tid] + EPS);
    float s2 = g2[tid] * rsqrtf(v2[tid] + EPS);
    float s3 = g3[tid] * rsqrtf(v3[tid] + EPS);
    bs1[tid] = b1[tid] - m1[tid] * s1;
    bs2[tid] = b2[tid] - m2[tid] * s2;
    bs3[tid] = b3[tid] - m3[tid] * s3;
  }
}

// ---------------------------------------------------------------- pack x
// x[b][ci][m] f32 (NCHW) -> xT[b][m][ci] bf16 (B^T layout for GEMM)
__global__ __launch_bounds__(256) void pack_x(const float* __restrict__ x, u16* __restrict__ xT) {
  __shared__ float tile[64][65];
  int mt = blockIdx.x, ct = blockIdx.y, b = blockIdx.z;
  const float* xp = x + ((size_t)b * CC + ct * 64) * HWSZ + mt * 64;
  for (int i = threadIdx.x; i < 4096; i += 256) {
    int r = i >> 6, c = i & 63;               // r = ci-local, c = m-local
    tile[r][c] = xp[(size_t)r * HWSZ + c];
  }
  __syncthreads();
  u16* op = xT + ((size_t)b * HWSZ + mt * 64) * CC + ct * 64;
  for (int i = threadIdx.x; i < 4096; i += 256) {
    int r = i >> 6, c = i & 63;               // r = m-local, c = ci-local
    op[(size_t)r * CC + c] = f2bf(tile[c][r]);
  }
}

// ---------------------------------------------------------------- GEMM (conv1 / conv3)
// Y[co][m] = sum_k A[co][k] * B[k][m];  A = folded weights [co][k] bf16,
// Bmat = [b][m][k] bf16 (B^T layout).  128x128 tile, BK=32, 4 waves (2x2),
// each wave 64x64 via 4x4 mfma_f32_16x16x32_bf16.
// MODE 0: out = y1 bf16 NCHW (bias+SiLU).  MODE 1: out f32 = SiLU(.)+shortcut.
template <int MODE>
__global__ __launch_bounds__(256) void gemm_kernel(
    const u16* __restrict__ Bmat, const u16* __restrict__ Amat,
    const float* __restrict__ bias, const float* __restrict__ shortcut,
    void* __restrict__ outp)
{
  __shared__ __align__(16) u16 As[4096];  // A[row 128][k 32]
  __shared__ __align__(16) u16 Bs[4096];  // Bt[n 128][k 32]
  int bid = blockIdx.x;
  int ct = bid & 7;          // co-tile
  int mt = (bid >> 3) & 31;  // m-tile
  int b  = bid >> 8;
  int t = threadIdx.x;
  int wv = t >> 6, lane = t & 63;
  int wr = wv >> 1, wc = wv & 1;
  const u16* Ap = Amat + (size_t)ct * 128 * 1024;
  const u16* Bp = Bmat + ((size_t)b * HWSZ + (size_t)mt * 128) * 1024;

  f32x4 acc[4][4] = {};
  int srow = t >> 2;            // 0..63
  int scol = (t & 3) << 3;      // 0,8,16,24
  int aoff = (wr * 64 + (lane & 15)) * 32 + ((lane >> 4) << 3);
  int boff = (wc * 64 + (lane & 15)) * 32 + ((lane >> 4) << 3);

  for (int k0 = 0; k0 < 1024; k0 += 32) {
    gload_lds16(Ap + (size_t)srow * 1024 + k0 + scol,        As + (wv * 64) * 8);
    gload_lds16(Bp + (size_t)srow * 1024 + k0 + scol,        Bs + (wv * 64) * 8);
    gload_lds16(Ap + (size_t)(srow + 64) * 1024 + k0 + scol, As + (256 + wv * 64) * 8);
    gload_lds16(Bp + (size_t)(srow + 64) * 1024 + k0 + scol, Bs + (256 + wv * 64) * 8);
    __syncthreads();
    u16x8 af[4], bfr[4];
#pragma unroll
    for (int i = 0; i < 4; ++i) {
      af[i]  = *(const u16x8*)&As[aoff + i * 16 * 32];
      bfr[i] = *(const u16x8*)&Bs[boff + i * 16 * 32];
    }
#pragma unroll
    for (int i = 0; i < 4; ++i)
#pragma unroll
      for (int j = 0; j < 4; ++j)
        acc[i][j] = __builtin_amdgcn_mfma_f32_16x16x32_bf16(
            __builtin_bit_cast(bf16x8, af[i]), __builtin_bit_cast(bf16x8, bfr[j]),
            acc[i][j], 0, 0, 0);
    __syncthreads();
  }

  // epilogue: C/D layout col=lane&15 (m), row=(lane>>4)*4+r (co)
  int cbase = ct * 128 + wr * 64 + ((lane >> 4) << 2);
  int mcol  = mt * 128 + wc * 64 + (lane & 15);
#pragma unroll
  for (int i = 0; i < 4; ++i) {
    int co0 = cbase + i * 16;
#pragma unroll
    for (int j = 0; j < 4; ++j) {
      int m = mcol + j * 16;
      size_t idx = ((size_t)b * CC + co0) * HWSZ + m;
      if (MODE == 0) {
        u16* y1 = (u16*)outp;
#pragma unroll
        for (int r = 0; r < 4; ++r) {
          float v = acc[i][j][r] + bias[co0 + r];
          y1[idx + (size_t)r * HWSZ] = f2bf(silu(v));
        }
      } else {
        float* op = (float*)outp;
#pragma unroll
        for (int r = 0; r < 4; ++r) {
          float v = acc[i][j][r] + bias[co0 + r];
          size_t ix = idx + (size_t)r * HWSZ;
          op[ix] = silu(v) + shortcut[ix];
        }
      }
    }
  }
}

// ---------------------------------------------------------------- attention
// Per (b,nh,h): S[k=hd][w] = y1[b, nh*64+k, h, w]; p = softmax over k per col w;
// att^T[v][w] = sum_k S[k][v]*P[k][w] * inv_sum[w]; write y2[b, nh*64+v, h, w].
__global__ __launch_bounds__(256) void attn_kernel(const u16* __restrict__ y1, u16* __restrict__ y2) {
  __shared__ __align__(16) float S[64][68];
  __shared__ __align__(16) float P[64][68];
  __shared__ __align__(16) float red[6][64];
  int bid = blockIdx.x;
  int h = bid & 63;
  int nh = (bid >> 6) & 15;
  int b = bid >> 10;
  const u16* base = y1 + ((size_t)b * CC + nh * 64) * HWSZ + h * 64;
  int t = threadIdx.x;
  for (int i = t; i < 4096; i += 256) {
    int k = i >> 6, w = i & 63;
    S[k][w] = bf2f(base[(size_t)k * HWSZ + w]);
  }
  __syncthreads();
  int w = t & 63, part = t >> 6;
  int k0 = part * 16;
  float mx = -1e30f;
  for (int k = k0; k < k0 + 16; ++k) mx = fmaxf(mx, S[k][w]);
  red[part][w] = mx;
  __syncthreads();
  mx = fmaxf(fmaxf(red[0][w], red[1][w]), fmaxf(red[2][w], red[3][w]));
  __syncthreads();
  float sm = 0.f;
  for (int k = k0; k < k0 + 16; ++k) {
    float e = __expf(S[k][w] - mx);
    P[k][w] = e;
    sm += e;
  }
  red[part][w] = sm;
  __syncthreads();
  if (part == 0) {
    float tot = red[0][w] + red[1][w] + red[2][w] + red[3][w];
    red[4][w] = 1.f / tot;
  }
  __syncthreads();

  int v0 = (t >> 4) << 2;   // 0..60
  int w0 = (t & 15) << 2;   // 0..60
  f32x4 acc0 = {0.f, 0.f, 0.f, 0.f}, acc1 = acc0, acc2 = acc0, acc3 = acc0;
  for (int k = 0; k < 64; ++k) {
    f32x4 pv = *(const f32x4*)&P[k][w0];
    f32x4 sv = *(const f32x4*)&S[k][v0];
    acc0 += sv.x * pv;
    acc1 += sv.y * pv;
    acc2 += sv.z * pv;
    acc3 += sv.w * pv;
  }
  f32x4 inv = *(const f32x4*)&red[4][w0];
  size_t ob = ((size_t)b * CC + nh * 64 + v0) * HWSZ + h * 64 + w0;
  f32x4 a;
  u16x4 q;
  a = acc0 * inv; q[0]=f2bf(a.x); q[1]=f2bf(a.y); q[2]=f2bf(a.z); q[3]=f2bf(a.w);
  *(u16x4*)&y2[ob] = q;
  a = acc1 * inv; q[0]=f2bf(a.x); q[1]=f2bf(a.y); q[2]=f2bf(a.z); q[3]=f2bf(a.w);
  *(u16x4*)&y2[ob + HWSZ] = q;
  a = acc2 * inv; q[0]=f2bf(a.x); q[1]=f2bf(a.y); q[2]=f2bf(a.z); q[3]=f2bf(a.w);
  *(u16x4*)&y2[ob + 2 * HWSZ] = q;
  a = acc3 * inv; q[0]=f2bf(a.x); q[1]=f2bf(a.y); q[2]=f2bf(a.z); q[3]=f2bf(a.w);
  *(u16x4*)&y2[ob + 3 * HWSZ] = q;
}

// ---------------------------------------------------------------- depthwise 3x3 + BN + SiLU
// reads y2 NCHW bf16; writes y3T[b][m][c] bf16 (B^T layout for conv3)
__global__ __launch_bounds__(256) void dwconv_kernel(
    const u16* __restrict__ y2, const float* __restrict__ w2f,
    const float* __restrict__ bias2, u16* __restrict__ y3T)
{
  __shared__ float T[64][65];
  int bid = blockIdx.x;
  int ctile = bid & 15;
  int h = (bid >> 4) & 63;
  int b = bid >> 10;
  int t = threadIdx.x;
  int cl = t >> 2;
  int wq = (t & 3) << 4;
  int c = ctile * 64 + cl;
  const u16* inp = y2 + ((size_t)b * CC + c) * HWSZ;
  const float* kw = w2f + c * 9;
  float k00=kw[0],k01=kw[1],k02=kw[2],k10=kw[3],k11=kw[4],k12=kw[5],k20=kw[6],k21=kw[7],k22=kw[8];
  float bb = bias2[c];
  float rb0[18], rb1[18], rb2[18];
#pragma unroll
  for (int j = 0; j < 18; ++j) {
    int ww = wq - 1 + j;
    bool wok = (ww >= 0) && (ww < 64);
    rb0[j] = (h >= 1 && wok) ? bf2f(inp[(h - 1) * 64 + ww]) : 0.f;
    rb1[j] = wok ? bf2f(inp[h * 64 + ww]) : 0.f;
    rb2[j] = (h < 63 && wok) ? bf2f(inp[(h + 1) * 64 + ww]) : 0.f;
  }
#pragma unroll
  for (int wi = 0; wi < 16; ++wi) {
    float acc = k00*rb0[wi] + k01*rb0[wi+1] + k02*rb0[wi+2]
              + k10*rb1[wi] + k11*rb1[wi+1] + k12*rb1[wi+2]
              + k20*rb2[wi] + k21*rb2[wi+1] + k22*rb2[wi+2];
    T[cl][wq + wi] = silu(acc + bb);
  }
  __syncthreads();
  int wrow = t >> 2;
  int cp = (t & 3) << 4;
  u16x8 o0, o1;
#pragma unroll
  for (int j = 0; j < 8; ++j) o0[j] = f2bf(T[cp + j][wrow]);
#pragma unroll
  for (int j = 0; j < 8; ++j) o1[j] = f2bf(T[cp + 8 + j][wrow]);
  size_t obase = ((size_t)b * HWSZ + h * 64 + wrow) * CC + ctile * 64 + cp;
  *(u16x8*)&y3T[obase] = o0;
  *(u16x8*)&y3T[obase + 8] = o1;
}

// ---------------------------------------------------------------- launch
extern "C" void kernel_launch(void* const* d_in, const int* in_sizes, int n_in,
                              void* d_out, int out_size, void* d_ws, size_t ws_size,
                              hipStream_t stream) {
  const float* x = (const float*)d_in[0];
  const float *w1, *w2, *w3, *g1, *b1, *m1, *v1, *g2, *b2, *m2, *v2, *g3, *b3, *m3, *v3;
  if (in_sizes[2] == 9216) {
    // setup_inputs() dict order: x, w1, w2, w3, g1,b1,m1,v1, g2,b2,m2,v2, g3,b3,m3,v3
    w1 = (const float*)d_in[1];  w2 = (const float*)d_in[2];  w3 = (const float*)d_in[3];
    g1 = (const float*)d_in[4];  b1 = (const float*)d_in[5];  m1 = (const float*)d_in[6];  v1 = (const float*)d_in[7];
    g2 = (const float*)d_in[8];  b2 = (const float*)d_in[9];  m2 = (const float*)d_in[10]; v2 = (const float*)d_in[11];
    g3 = (const float*)d_in[12]; b3 = (const float*)d_in[13]; m3 = (const float*)d_in[14]; v3 = (const float*)d_in[15];
  } else {
    // reference() signature order
    w1 = (const float*)d_in[1];  g1 = (const float*)d_in[2];  b1 = (const float*)d_in[3];  m1 = (const float*)d_in[4];  v1 = (const float*)d_in[5];
    w2 = (const float*)d_in[6];  g2 = (const float*)d_in[7];  b2 = (const float*)d_in[8];  m2 = (const float*)d_in[9];  v2 = (const float*)d_in[10];
    w3 = (const float*)d_in[11]; g3 = (const float*)d_in[12]; b3 = (const float*)d_in[13]; m3 = (const float*)d_in[14]; v3 = (const float*)d_in[15];
  }

  char* ws = (char*)d_ws;
  u16*   bufA = (u16*)ws;                              // 33,554,432 elems (67 MB): xT, later y2
  u16*   bufB = (u16*)(ws + 67108864);                 // y1, later y3T
  u16*   w1f  = (u16*)(ws + 134217728);
  u16*   w3f  = (u16*)(ws + 134217728 + 2097152);
  float* w2f  = (float*)(ws + 134217728 + 4194304);
  float* bs1  = (float*)(ws + 138448896);
  float* bs2  = (float*)(ws + 138452992);
  float* bs3  = (float*)(ws + 138457088);

  prep_kernel<<<2048, 256, 0, stream>>>(w1, w2, w3, g1, b1, m1, v1, g2, b2, m2, v2,
                                        g3, b3, m3, v3, w1f, w3f, w2f, bs1, bs2, bs3);
  pack_x<<<dim3(64, 16, 8), 256, 0, stream>>>(x, bufA);
  gemm_kernel<0><<<2048, 256, 0, stream>>>(bufA, w1f, bs1, nullptr, bufB);
  attn_kernel<<<8192, 256, 0, stream>>>(bufB, bufA);
  dwconv_kernel<<<8192, 256, 0, stream>>>(bufA, w2f, bs2, bufB);
  gemm_kernel<1><<<2048, 256, 0, stream>>>(bufB, w3f, bs3, x, d_out);
}

// Round 2
// 590.097 us; speedup vs baseline: 1.3002x; 1.3002x over previous
//
#include <hip/hip_runtime.h>

typedef unsigned short u16;
typedef unsigned int u32;
typedef __attribute__((ext_vector_type(4))) float f32x4;
typedef __attribute__((ext_vector_type(8))) u16 u16x8;
typedef __attribute__((ext_vector_type(4))) u16 u16x4;
typedef __attribute__((ext_vector_type(4))) u32 u32x4;
typedef __attribute__((ext_vector_type(8))) __bf16 bf16x8;

#define BB 8
#define CC 1024
#define HWSZ 4096
#define EPS 1e-3f

__device__ __forceinline__ u16 f2bf(float f) {
  union { float f; unsigned u; } v; v.f = f;
  unsigned r = v.u + 0x7FFFu + ((v.u >> 16) & 1u);
  return (u16)(r >> 16);
}
__device__ __forceinline__ float bf2f(u16 h) {
  union { unsigned u; float f; } v; v.u = ((unsigned)h) << 16;
  return v.f;
}
__device__ __forceinline__ float silu(float v) {
  return v / (1.0f + __expf(-v));
}
__device__ __forceinline__ void gload_lds16(const void* g, void* l) {
  __builtin_amdgcn_global_load_lds((const __attribute__((address_space(1))) void*)g,
                                   (__attribute__((address_space(3))) void*)l, 16, 0, 0);
}

// ---------------------------------------------------------------- prep
__global__ __launch_bounds__(256) void prep_kernel(
    const float* __restrict__ w1, const float* __restrict__ w2, const float* __restrict__ w3,
    const float* __restrict__ g1, const float* __restrict__ b1, const float* __restrict__ m1, const float* __restrict__ v1,
    const float* __restrict__ g2, const float* __restrict__ b2, const float* __restrict__ m2, const float* __restrict__ v2,
    const float* __restrict__ g3, const float* __restrict__ b3, const float* __restrict__ m3, const float* __restrict__ v3,
    u16* __restrict__ w1f, u16* __restrict__ w3f, float* __restrict__ w2f,
    float* __restrict__ bs1, float* __restrict__ bs2, float* __restrict__ bs3)
{
  int tid = blockIdx.x * 256 + threadIdx.x;
  int stride = gridDim.x * 256;
  for (int i = tid; i < 1048576; i += stride) {
    int co = i >> 10;
    float s1 = g1[co] * rsqrtf(v1[co] + EPS);
    float s3 = g3[co] * rsqrtf(v3[co] + EPS);
    w1f[i] = f2bf(w1[i] * s1);
    w3f[i] = f2bf(w3[i] * s3);
  }
  if (tid < 9216) {
    int c = tid / 9;
    float s2 = g2[c] * rsqrtf(v2[c] + EPS);
    w2f[tid] = w2[tid] * s2;
  }
  if (tid < 1024) {
    float s1 = g1[tid] * rsqrtf(v1[tid] + EPS);
    float s2 = g2[tid] * rsqrtf(v2[tid] + EPS);
    float s3 = g3[tid] * rsqrtf(v3[tid] + EPS);
    bs1[tid] = b1[tid] - m1[tid] * s1;
    bs2[tid] = b2[tid] - m2[tid] * s2;
    bs3[tid] = b3[tid] - m3[tid] * s3;
  }
}

// ---------------------------------------------------------------- pack x
// x[b][ci][m] f32 (NCHW) -> xT[b][m][ci] bf16
__global__ __launch_bounds__(256) void pack_x(const float* __restrict__ x, u16* __restrict__ xT) {
  __shared__ float tile[64][65];
  int mt = blockIdx.x, ct = blockIdx.y, b = blockIdx.z;
  const float* xp = x + ((size_t)b * CC + ct * 64) * HWSZ + mt * 64;
  for (int i = threadIdx.x; i < 4096; i += 256) {
    int r = i >> 6, c = i & 63;
    tile[r][c] = xp[(size_t)r * HWSZ + c];
  }
  __syncthreads();
  u16* op = xT + ((size_t)b * HWSZ + mt * 64) * CC + ct * 64;
  for (int i = threadIdx.x; i < 4096; i += 256) {
    int r = i >> 6, c = i & 63;
    op[(size_t)r * CC + c] = f2bf(tile[c][r]);
  }
}

// ---------------------------------------------------------------- GEMM (conv1 / conv3)
template <int MODE>
__global__ __launch_bounds__(256) void gemm_kernel(
    const u16* __restrict__ Bmat, const u16* __restrict__ Amat,
    const float* __restrict__ bias, const float* __restrict__ shortcut,
    void* __restrict__ outp)
{
  __shared__ __align__(16) u16 As[4096];
  __shared__ __align__(16) u16 Bs[4096];
  int bid = blockIdx.x;
  int ct = bid & 7;
  int mt = (bid >> 3) & 31;
  int b  = bid >> 8;
  int t = threadIdx.x;
  int wv = t >> 6, lane = t & 63;
  int wr = wv >> 1, wc = wv & 1;
  const u16* Ap = Amat + (size_t)ct * 128 * 1024;
  const u16* Bp = Bmat + ((size_t)b * HWSZ + (size_t)mt * 128) * 1024;

  f32x4 acc[4][4] = {};
  int srow = t >> 2;
  int scol = (t & 3) << 3;
  int aoff = (wr * 64 + (lane & 15)) * 32 + ((lane >> 4) << 3);
  int boff = (wc * 64 + (lane & 15)) * 32 + ((lane >> 4) << 3);

  for (int k0 = 0; k0 < 1024; k0 += 32) {
    gload_lds16(Ap + (size_t)srow * 1024 + k0 + scol,        As + (wv * 64) * 8);
    gload_lds16(Bp + (size_t)srow * 1024 + k0 + scol,        Bs + (wv * 64) * 8);
    gload_lds16(Ap + (size_t)(srow + 64) * 1024 + k0 + scol, As + (256 + wv * 64) * 8);
    gload_lds16(Bp + (size_t)(srow + 64) * 1024 + k0 + scol, Bs + (256 + wv * 64) * 8);
    __syncthreads();
    u16x8 af[4], bfr[4];
#pragma unroll
    for (int i = 0; i < 4; ++i) {
      af[i]  = *(const u16x8*)&As[aoff + i * 16 * 32];
      bfr[i] = *(const u16x8*)&Bs[boff + i * 16 * 32];
    }
#pragma unroll
    for (int i = 0; i < 4; ++i)
#pragma unroll
      for (int j = 0; j < 4; ++j)
        acc[i][j] = __builtin_amdgcn_mfma_f32_16x16x32_bf16(
            __builtin_bit_cast(bf16x8, af[i]), __builtin_bit_cast(bf16x8, bfr[j]),
            acc[i][j], 0, 0, 0);
    __syncthreads();
  }

  int cbase = ct * 128 + wr * 64 + ((lane >> 4) << 2);
  int mcol  = mt * 128 + wc * 64 + (lane & 15);
#pragma unroll
  for (int i = 0; i < 4; ++i) {
    int co0 = cbase + i * 16;
#pragma unroll
    for (int j = 0; j < 4; ++j) {
      int m = mcol + j * 16;
      size_t idx = ((size_t)b * CC + co0) * HWSZ + m;
      if (MODE == 0) {
        u16* y1 = (u16*)outp;
#pragma unroll
        for (int r = 0; r < 4; ++r) {
          float v = acc[i][j][r] + bias[co0 + r];
          y1[idx + (size_t)r * HWSZ] = f2bf(silu(v));
        }
      } else {
        float* op = (float*)outp;
#pragma unroll
        for (int r = 0; r < 4; ++r) {
          float v = acc[i][j][r] + bias[co0 + r];
          size_t ix = idx + (size_t)r * HWSZ;
          op[ix] = silu(v) + shortcut[ix];
        }
      }
    }
  }
}

// ---------------------------------------------------------------- attention (MFMA)
// Per block (b,nh,h): St[w][k] = y1[b, nh*64+k, h, w]  (bf16, pad stride 72).
// Wave wv: softmax stats for rows w=wv*16+(lane&15) fully in-register via shfl;
// B-frag = exp(s-mx) packed bf16 from the SAME u16x8 chunks; A-frag = St rows v.
// out[v][w] = (sum_k S[k][v] * P[k][w]) * inv[w];  D col=lane&15 (w), row=(lane>>4)*4+r (v).
__global__ __launch_bounds__(256) void attn_kernel(const u16* __restrict__ y1, u16* __restrict__ y2) {
  __shared__ __align__(16) u16 St[64 * 72];
  int bid = blockIdx.x;
  int h = bid & 63;
  int nh = (bid >> 6) & 15;
  int b = bid >> 10;
  const u16* base = y1 + ((size_t)b * CC + nh * 64) * HWSZ + h * 64;
  int t = threadIdx.x;

  // stage + transpose: thread t handles chunks t and t+256; chunk g = (k=g>>3, w8=g&7)
#pragma unroll
  for (int it = 0; it < 2; ++it) {
    int g = t + it * 256;
    int k = g >> 3, w8 = g & 7;
    u16x8 v = *(const u16x8*)&base[(size_t)k * HWSZ + w8 * 8];
#pragma unroll
    for (int e = 0; e < 8; ++e) St[(w8 * 8 + e) * 72 + k] = v[e];
  }
  __syncthreads();

  int wv = t >> 6, lane = t & 63;
  int r = lane & 15, q = lane >> 4;
  int w = wv * 16 + r;

  // row chunks for this lane's w: k = q*8..q*8+7 and (q+4)*8..(q+4)*8+7
  u16x8 s0 = *(const u16x8*)&St[w * 72 + q * 8];
  u16x8 s1 = *(const u16x8*)&St[w * 72 + (q + 4) * 8];
  float f0[8], f1[8];
#pragma unroll
  for (int j = 0; j < 8; ++j) { f0[j] = bf2f(s0[j]); f1[j] = bf2f(s1[j]); }
  float mx = -1e30f;
#pragma unroll
  for (int j = 0; j < 8; ++j) mx = fmaxf(mx, fmaxf(f0[j], f1[j]));
  mx = fmaxf(mx, __shfl_xor(mx, 16));
  mx = fmaxf(mx, __shfl_xor(mx, 32));
  float p0[8], p1[8], sm = 0.f;
#pragma unroll
  for (int j = 0; j < 8; ++j) { p0[j] = __expf(f0[j] - mx); p1[j] = __expf(f1[j] - mx); sm += p0[j] + p1[j]; }
  sm += __shfl_xor(sm, 16);
  sm += __shfl_xor(sm, 32);
  float inv = 1.0f / sm;

  // pack P chunks to bf16 fragments
  u16x8 pb0, pb1;
#pragma unroll
  for (int j = 0; j < 8; ++j) { pb0[j] = f2bf(p0[j]); pb1[j] = f2bf(p1[j]); }

  f32x4 acc[4] = {};
#pragma unroll
  for (int ks = 0; ks < 2; ++ks) {
    bf16x8 bfrag = __builtin_bit_cast(bf16x8, ks ? pb1 : pb0);
#pragma unroll
    for (int i = 0; i < 4; ++i) {
      u16x8 af = *(const u16x8*)&St[(i * 16 + r) * 72 + (ks * 4 + q) * 8];
      acc[i] = __builtin_amdgcn_mfma_f32_16x16x32_bf16(
          __builtin_bit_cast(bf16x8, af), bfrag, acc[i], 0, 0, 0);
    }
  }

  // epilogue: v = i*16 + q*4 + rr, w_global = h*64 + wv*16 + r
  size_t ob = ((size_t)b * CC + nh * 64) * HWSZ + h * 64 + wv * 16 + r;
#pragma unroll
  for (int i = 0; i < 4; ++i) {
#pragma unroll
    for (int rr = 0; rr < 4; ++rr) {
      int v = i * 16 + q * 4 + rr;
      y2[ob + (size_t)v * HWSZ] = f2bf(acc[i][rr] * inv);
    }
  }
}

// ---------------------------------------------------------------- depthwise 3x3 + BN + SiLU
// LDS-staged: Sm[r][c][w] (stride 66, zero-filled invalid rows), compute from LDS,
// transpose via T, vector-write y3T[b][m][c].
__global__ __launch_bounds__(256) void dwconv_kernel(
    const u16* __restrict__ y2, const float* __restrict__ w2f,
    const float* __restrict__ bias2, u16* __restrict__ y3T)
{
  __shared__ u16 Sm[3 * 64 * 66];
  __shared__ float T[64][65];
  int bid = blockIdx.x;
  int ctile = bid & 15;
  int h = (bid >> 4) & 63;
  int b = bid >> 10;
  int t = threadIdx.x;

  const u16* ybase = y2 + ((size_t)(b * CC + ctile * 64)) * HWSZ;
#pragma unroll
  for (int it = 0; it < 6; ++it) {
    int g = t + it * 256;           // 0..1535
    int c = g / 24;
    int rem = g - c * 24;
    int r = rem >> 3;
    int ch8 = rem & 7;
    int hh = h - 1 + r;
    u32x4 vv = {0u, 0u, 0u, 0u};
    if (hh >= 0 && hh < 64)
      vv = __builtin_bit_cast(u32x4, *(const u16x8*)&ybase[(size_t)c * HWSZ + hh * 64 + ch8 * 8]);
    u32* dst = (u32*)&Sm[(r * 64 + c) * 66 + ch8 * 8];
    dst[0] = vv[0]; dst[1] = vv[1]; dst[2] = vv[2]; dst[3] = vv[3];
  }
  __syncthreads();

  int cl = t >> 2;
  int wq = (t & 3) << 4;
  int c = ctile * 64 + cl;
  const float* kw = w2f + c * 9;
  float k00=kw[0],k01=kw[1],k02=kw[2],k10=kw[3],k11=kw[4],k12=kw[5],k20=kw[6],k21=kw[7],k22=kw[8];
  float bb = bias2[c];

  float rb0[18], rb1[18], rb2[18];
#pragma unroll
  for (int j = 0; j < 18; ++j) {
    int ww = wq - 1 + j;
    bool wok = (ww >= 0) && (ww < 64);
    int wc2 = wok ? ww : 0;
    float a0 = bf2f(Sm[(0 * 64 + cl) * 66 + wc2]);
    float a1 = bf2f(Sm[(1 * 64 + cl) * 66 + wc2]);
    float a2 = bf2f(Sm[(2 * 64 + cl) * 66 + wc2]);
    rb0[j] = wok ? a0 : 0.f;
    rb1[j] = wok ? a1 : 0.f;
    rb2[j] = wok ? a2 : 0.f;
  }
#pragma unroll
  for (int wi = 0; wi < 16; ++wi) {
    float acc = k00*rb0[wi] + k01*rb0[wi+1] + k02*rb0[wi+2]
              + k10*rb1[wi] + k11*rb1[wi+1] + k12*rb1[wi+2]
              + k20*rb2[wi] + k21*rb2[wi+1] + k22*rb2[wi+2];
    T[cl][wq + wi] = silu(acc + bb);
  }
  __syncthreads();
  int wrow = t >> 2;
  int cp = (t & 3) << 4;
  u16x8 o0, o1;
#pragma unroll
  for (int j = 0; j < 8; ++j) o0[j] = f2bf(T[cp + j][wrow]);
#pragma unroll
  for (int j = 0; j < 8; ++j) o1[j] = f2bf(T[cp + 8 + j][wrow]);
  size_t obase = ((size_t)b * HWSZ + h * 64 + wrow) * CC + ctile * 64 + cp;
  *(u16x8*)&y3T[obase] = o0;
  *(u16x8*)&y3T[obase + 8] = o1;
}

// ---------------------------------------------------------------- launch
extern "C" void kernel_launch(void* const* d_in, const int* in_sizes, int n_in,
                              void* d_out, int out_size, void* d_ws, size_t ws_size,
                              hipStream_t stream) {
  const float* x = (const float*)d_in[0];
  const float *w1, *w2, *w3, *g1, *b1, *m1, *v1, *g2, *b2, *m2, *v2, *g3, *b3, *m3, *v3;
  if (in_sizes[2] == 9216) {
    w1 = (const float*)d_in[1];  w2 = (const float*)d_in[2];  w3 = (const float*)d_in[3];
    g1 = (const float*)d_in[4];  b1 = (const float*)d_in[5];  m1 = (const float*)d_in[6];  v1 = (const float*)d_in[7];
    g2 = (const float*)d_in[8];  b2 = (const float*)d_in[9];  m2 = (const float*)d_in[10]; v2 = (const float*)d_in[11];
    g3 = (const float*)d_in[12]; b3 = (const float*)d_in[13]; m3 = (const float*)d_in[14]; v3 = (const float*)d_in[15];
  } else {
    w1 = (const float*)d_in[1];  g1 = (const float*)d_in[2];  b1 = (const float*)d_in[3];  m1 = (const float*)d_in[4];  v1 = (const float*)d_in[5];
    w2 = (const float*)d_in[6];  g2 = (const float*)d_in[7];  b2 = (const float*)d_in[8];  m2 = (const float*)d_in[9];  v2 = (const float*)d_in[10];
    w3 = (const float*)d_in[11]; g3 = (const float*)d_in[12]; b3 = (const float*)d_in[13]; m3 = (const float*)d_in[14]; v3 = (const float*)d_in[15];
  }

  char* ws = (char*)d_ws;
  u16*   bufA = (u16*)ws;
  u16*   bufB = (u16*)(ws + 67108864);
  u16*   w1f  = (u16*)(ws + 134217728);
  u16*   w3f  = (u16*)(ws + 134217728 + 2097152);
  float* w2f  = (float*)(ws + 134217728 + 4194304);
  float* bs1  = (float*)(ws + 138448896);
  float* bs2  = (float*)(ws + 138452992);
  float* bs3  = (float*)(ws + 138457088);

  prep_kernel<<<2048, 256, 0, stream>>>(w1, w2, w3, g1, b1, m1, v1, g2, b2, m2, v2,
                                        g3, b3, m3, v3, w1f, w3f, w2f, bs1, bs2, bs3);
  pack_x<<<dim3(64, 16, 8), 256, 0, stream>>>(x, bufA);
  gemm_kernel<0><<<2048, 256, 0, stream>>>(bufA, w1f, bs1, nullptr, bufB);
  attn_kernel<<<8192, 256, 0, stream>>>(bufB, bufA);
  dwconv_kernel<<<8192, 256, 0, stream>>>(bufA, w2f, bs2, bufB);
  gemm_kernel<1><<<2048, 256, 0, stream>>>(bufB, w3f, bs3, x, d_out);
}

// Round 3
// 563.998 us; speedup vs baseline: 1.3603x; 1.0463x over previous
//
#include <hip/hip_runtime.h>

typedef unsigned short u16;
typedef unsigned int u32;
typedef __attribute__((ext_vector_type(4))) float f32x4;
typedef __attribute__((ext_vector_type(8))) u16 u16x8;
typedef __attribute__((ext_vector_type(4))) u16 u16x4;
typedef __attribute__((ext_vector_type(4))) u32 u32x4;
typedef __attribute__((ext_vector_type(8))) __bf16 bf16x8;

#define BB 8
#define CC 1024
#define HWSZ 4096
#define EPS 1e-3f

__device__ __forceinline__ u16 f2bf(float f) {
  union { float f; unsigned u; } v; v.f = f;
  unsigned r = v.u + 0x7FFFu + ((v.u >> 16) & 1u);
  return (u16)(r >> 16);
}
__device__ __forceinline__ float bf2f(u16 h) {
  union { unsigned u; float f; } v; v.u = ((unsigned)h) << 16;
  return v.f;
}
__device__ __forceinline__ float silu(float v) {
  return v / (1.0f + __expf(-v));
}
__device__ __forceinline__ void gload_lds16(const void* g, void* l) {
  __builtin_amdgcn_global_load_lds((const __attribute__((address_space(1))) void*)g,
                                   (__attribute__((address_space(3))) void*)l, 16, 0, 0);
}

// ---------------------------------------------------------------- prep
__global__ __launch_bounds__(256) void prep_kernel(
    const float* __restrict__ w1, const float* __restrict__ w2, const float* __restrict__ w3,
    const float* __restrict__ g1, const float* __restrict__ b1, const float* __restrict__ m1, const float* __restrict__ v1,
    const float* __restrict__ g2, const float* __restrict__ b2, const float* __restrict__ m2, const float* __restrict__ v2,
    const float* __restrict__ g3, const float* __restrict__ b3, const float* __restrict__ m3, const float* __restrict__ v3,
    u16* __restrict__ w1f, u16* __restrict__ w3f, float* __restrict__ w2f,
    float* __restrict__ bs1, float* __restrict__ bs2, float* __restrict__ bs3)
{
  int tid = blockIdx.x * 256 + threadIdx.x;
  int stride = gridDim.x * 256;
  for (int i = tid; i < 1048576; i += stride) {
    int co = i >> 10;
    float s1 = g1[co] * rsqrtf(v1[co] + EPS);
    float s3 = g3[co] * rsqrtf(v3[co] + EPS);
    w1f[i] = f2bf(w1[i] * s1);
    w3f[i] = f2bf(w3[i] * s3);
  }
  if (tid < 9216) {
    int c = tid / 9;
    float s2 = g2[c] * rsqrtf(v2[c] + EPS);
    w2f[tid] = w2[tid] * s2;
  }
  if (tid < 1024) {
    float s1 = g1[tid] * rsqrtf(v1[tid] + EPS);
    float s2 = g2[tid] * rsqrtf(v2[tid] + EPS);
    float s3 = g3[tid] * rsqrtf(v3[tid] + EPS);
    bs1[tid] = b1[tid] - m1[tid] * s1;
    bs2[tid] = b2[tid] - m2[tid] * s2;
    bs3[tid] = b3[tid] - m3[tid] * s3;
  }
}

// ---------------------------------------------------------------- pack x
// x[b][ci][m] f32 (NCHW) -> xT[b][m][ci] bf16
__global__ __launch_bounds__(256) void pack_x(const float* __restrict__ x, u16* __restrict__ xT) {
  __shared__ float tile[64][65];
  int mt = blockIdx.x, ct = blockIdx.y, b = blockIdx.z;
  const float* xp = x + ((size_t)b * CC + ct * 64) * HWSZ + mt * 64;
  for (int i = threadIdx.x; i < 4096; i += 256) {
    int r = i >> 6, c = i & 63;
    tile[r][c] = xp[(size_t)r * HWSZ + c];
  }
  __syncthreads();
  u16* op = xT + ((size_t)b * HWSZ + mt * 64) * CC + ct * 64;
  for (int i = threadIdx.x; i < 4096; i += 256) {
    int r = i >> 6, c = i & 63;
    op[(size_t)r * CC + c] = f2bf(tile[c][r]);
  }
}

// ---------------------------------------------------------------- GEMM (conv1 / conv3)
// Y[co][m] = sum_k A[co][k]*B[k][m]; A=[co][k] bf16, Bmat=[b][m][k] bf16 (B^T).
// 128x128 tile, BK=32, 4 waves (2x2).
// bid = [b(3)][mt_hi(2)][ct(3)][mt_lo(3)]: xcd = bid%8 = mt_lo pins each
// B-panel to one XCD; ct sweeps 0..7 back-to-back on that XCD (B-panel +
// whole A fit its 4 MB L2 -> B streams from HBM once).
// MODE 0: out y1T[b][m][co] bf16 (bias+SiLU).  MODE 1: out f32 NCHW = SiLU+shortcut.
template <int MODE>
__global__ __launch_bounds__(256) void gemm_kernel(
    const u16* __restrict__ Bmat, const u16* __restrict__ Amat,
    const float* __restrict__ bias, const float* __restrict__ shortcut,
    void* __restrict__ outp)
{
  __shared__ __align__(16) u16 As[4096];
  __shared__ __align__(16) u16 Bs[4096];
  int bid = blockIdx.x;
  int mt_lo = bid & 7;
  int ct = (bid >> 3) & 7;
  int mt_hi = (bid >> 6) & 3;
  int b = bid >> 8;
  int mt = (mt_hi << 3) | mt_lo;
  int t = threadIdx.x;
  int wv = t >> 6, lane = t & 63;
  int wr = wv >> 1, wc = wv & 1;
  const u16* Ap = Amat + (size_t)ct * 128 * 1024;
  const u16* Bp = Bmat + ((size_t)b * HWSZ + (size_t)mt * 128) * 1024;

  f32x4 acc[4][4] = {};
  int srow = t >> 2;
  int scol = (t & 3) << 3;
  int aoff = (wr * 64 + (lane & 15)) * 32 + ((lane >> 4) << 3);
  int boff = (wc * 64 + (lane & 15)) * 32 + ((lane >> 4) << 3);

  for (int k0 = 0; k0 < 1024; k0 += 32) {
    gload_lds16(Ap + (size_t)srow * 1024 + k0 + scol,        As + (wv * 64) * 8);
    gload_lds16(Bp + (size_t)srow * 1024 + k0 + scol,        Bs + (wv * 64) * 8);
    gload_lds16(Ap + (size_t)(srow + 64) * 1024 + k0 + scol, As + (256 + wv * 64) * 8);
    gload_lds16(Bp + (size_t)(srow + 64) * 1024 + k0 + scol, Bs + (256 + wv * 64) * 8);
    __syncthreads();
    u16x8 af[4], bfr[4];
#pragma unroll
    for (int i = 0; i < 4; ++i) {
      af[i]  = *(const u16x8*)&As[aoff + i * 16 * 32];
      bfr[i] = *(const u16x8*)&Bs[boff + i * 16 * 32];
    }
#pragma unroll
    for (int i = 0; i < 4; ++i)
#pragma unroll
      for (int j = 0; j < 4; ++j)
        acc[i][j] = __builtin_amdgcn_mfma_f32_16x16x32_bf16(
            __builtin_bit_cast(bf16x8, af[i]), __builtin_bit_cast(bf16x8, bfr[j]),
            acc[i][j], 0, 0, 0);
    __syncthreads();
  }

  // C/D layout: col = lane&15 (m), row = (lane>>4)*4 + r (co)
  int cbase = ct * 128 + wr * 64 + ((lane >> 4) << 2);
  int mcol  = mt * 128 + wc * 64 + (lane & 15);
#pragma unroll
  for (int i = 0; i < 4; ++i) {
    int co0 = cbase + i * 16;
#pragma unroll
    for (int j = 0; j < 4; ++j) {
      int m = mcol + j * 16;
      if (MODE == 0) {
        // y1T[b][m][co] bf16: 4 consecutive co -> one 8B store
        u16* y1 = (u16*)outp;
        u16x4 pk;
#pragma unroll
        for (int r = 0; r < 4; ++r) {
          float v = acc[i][j][r] + bias[co0 + r];
          pk[r] = f2bf(silu(v));
        }
        *(u16x4*)&y1[((size_t)b * HWSZ + m) * CC + co0] = pk;
      } else {
        float* op = (float*)outp;
        size_t idx = ((size_t)b * CC + co0) * HWSZ + m;
#pragma unroll
        for (int r = 0; r < 4; ++r) {
          float v = acc[i][j][r] + bias[co0 + r];
          size_t ix = idx + (size_t)r * HWSZ;
          op[ix] = silu(v) + shortcut[ix];
        }
      }
    }
  }
}

// ---------------------------------------------------------------- attention (MFMA)
// y1T[b][m][co] layout: row (b, m=h*64+w) slice [nh*64 .. nh*64+63] is St[w][:],
// contiguous 128B -> coalesced u16x8 loads + vector ds_write (stride 72 = 144B,
// 16B aligned, 2-way banks = free).
__global__ __launch_bounds__(256) void attn_kernel(const u16* __restrict__ y1T, u16* __restrict__ y2) {
  __shared__ __align__(16) u16 St[64 * 72];
  int bid = blockIdx.x;
  int h = bid & 63;
  int nh = (bid >> 6) & 15;
  int b = bid >> 10;
  const u16* base = y1T + ((size_t)b * HWSZ + h * 64) * CC + nh * 64;
  int t = threadIdx.x;

#pragma unroll
  for (int it = 0; it < 2; ++it) {
    int g = t + it * 256;        // 0..511
    int w = g >> 3, k8 = g & 7;
    u16x8 v = *(const u16x8*)&base[(size_t)w * CC + k8 * 8];
    *(u16x8*)&St[w * 72 + k8 * 8] = v;
  }
  __syncthreads();

  int wv = t >> 6, lane = t & 63;
  int r = lane & 15, q = lane >> 4;
  int w = wv * 16 + r;

  u16x8 s0 = *(const u16x8*)&St[w * 72 + q * 8];
  u16x8 s1 = *(const u16x8*)&St[w * 72 + (q + 4) * 8];
  float f0[8], f1[8];
#pragma unroll
  for (int j = 0; j < 8; ++j) { f0[j] = bf2f(s0[j]); f1[j] = bf2f(s1[j]); }
  float mx = -1e30f;
#pragma unroll
  for (int j = 0; j < 8; ++j) mx = fmaxf(mx, fmaxf(f0[j], f1[j]));
  mx = fmaxf(mx, __shfl_xor(mx, 16));
  mx = fmaxf(mx, __shfl_xor(mx, 32));
  float p0[8], p1[8], sm = 0.f;
#pragma unroll
  for (int j = 0; j < 8; ++j) { p0[j] = __expf(f0[j] - mx); p1[j] = __expf(f1[j] - mx); sm += p0[j] + p1[j]; }
  sm += __shfl_xor(sm, 16);
  sm += __shfl_xor(sm, 32);
  float inv = 1.0f / sm;

  u16x8 pb0, pb1;
#pragma unroll
  for (int j = 0; j < 8; ++j) { pb0[j] = f2bf(p0[j]); pb1[j] = f2bf(p1[j]); }

  f32x4 acc[4] = {};
#pragma unroll
  for (int ks = 0; ks < 2; ++ks) {
    bf16x8 bfrag = __builtin_bit_cast(bf16x8, ks ? pb1 : pb0);
#pragma unroll
    for (int i = 0; i < 4; ++i) {
      u16x8 af = *(const u16x8*)&St[(i * 16 + r) * 72 + (ks * 4 + q) * 8];
      acc[i] = __builtin_amdgcn_mfma_f32_16x16x32_bf16(
          __builtin_bit_cast(bf16x8, af), bfrag, acc[i], 0, 0, 0);
    }
  }

  // out[v][w] (v = i*16 + q*4 + rr), w_global = h*64 + wv*16 + r; y2 NCHW
  size_t ob = ((size_t)b * CC + nh * 64) * HWSZ + h * 64 + wv * 16 + r;
#pragma unroll
  for (int i = 0; i < 4; ++i) {
#pragma unroll
    for (int rr = 0; rr < 4; ++rr) {
      int v = i * 16 + q * 4 + rr;
      y2[ob + (size_t)v * HWSZ] = f2bf(acc[i][rr] * inv);
    }
  }
}

// ---------------------------------------------------------------- depthwise 3x3 + BN + SiLU
__global__ __launch_bounds__(256) void dwconv_kernel(
    const u16* __restrict__ y2, const float* __restrict__ w2f,
    const float* __restrict__ bias2, u16* __restrict__ y3T)
{
  __shared__ u16 Sm[3 * 64 * 66];
  __shared__ float T[64][65];
  int bid = blockIdx.x;
  int ctile = bid & 15;
  int h = (bid >> 4) & 63;
  int b = bid >> 10;
  int t = threadIdx.x;

  const u16* ybase = y2 + ((size_t)(b * CC + ctile * 64)) * HWSZ;
#pragma unroll
  for (int it = 0; it < 6; ++it) {
    int g = t + it * 256;
    int c = g / 24;
    int rem = g - c * 24;
    int r = rem >> 3;
    int ch8 = rem & 7;
    int hh = h - 1 + r;
    u32x4 vv = {0u, 0u, 0u, 0u};
    if (hh >= 0 && hh < 64)
      vv = __builtin_bit_cast(u32x4, *(const u16x8*)&ybase[(size_t)c * HWSZ + hh * 64 + ch8 * 8]);
    u32* dst = (u32*)&Sm[(r * 64 + c) * 66 + ch8 * 8];
    dst[0] = vv[0]; dst[1] = vv[1]; dst[2] = vv[2]; dst[3] = vv[3];
  }
  __syncthreads();

  int cl = t >> 2;
  int wq = (t & 3) << 4;
  int c = ctile * 64 + cl;
  const float* kw = w2f + c * 9;
  float k00=kw[0],k01=kw[1],k02=kw[2],k10=kw[3],k11=kw[4],k12=kw[5],k20=kw[6],k21=kw[7],k22=kw[8];
  float bb = bias2[c];

  float rb0[18], rb1[18], rb2[18];
#pragma unroll
  for (int j = 0; j < 18; ++j) {
    int ww = wq - 1 + j;
    bool wok = (ww >= 0) && (ww < 64);
    int wc2 = wok ? ww : 0;
    float a0 = bf2f(Sm[(0 * 64 + cl) * 66 + wc2]);
    float a1 = bf2f(Sm[(1 * 64 + cl) * 66 + wc2]);
    float a2 = bf2f(Sm[(2 * 64 + cl) * 66 + wc2]);
    rb0[j] = wok ? a0 : 0.f;
    rb1[j] = wok ? a1 : 0.f;
    rb2[j] = wok ? a2 : 0.f;
  }
#pragma unroll
  for (int wi = 0; wi < 16; ++wi) {
    float acc = k00*rb0[wi] + k01*rb0[wi+1] + k02*rb0[wi+2]
              + k10*rb1[wi] + k11*rb1[wi+1] + k12*rb1[wi+2]
              + k20*rb2[wi] + k21*rb2[wi+1] + k22*rb2[wi+2];
    T[cl][wq + wi] = silu(acc + bb);
  }
  __syncthreads();
  int wrow = t >> 2;
  int cp = (t & 3) << 4;
  u16x8 o0, o1;
#pragma unroll
  for (int j = 0; j < 8; ++j) o0[j] = f2bf(T[cp + j][wrow]);
#pragma unroll
  for (int j = 0; j < 8; ++j) o1[j] = f2bf(T[cp + 8 + j][wrow]);
  size_t obase = ((size_t)b * HWSZ + h * 64 + wrow) * CC + ctile * 64 + cp;
  *(u16x8*)&y3T[obase] = o0;
  *(u16x8*)&y3T[obase + 8] = o1;
}

// ---------------------------------------------------------------- launch
extern "C" void kernel_launch(void* const* d_in, const int* in_sizes, int n_in,
                              void* d_out, int out_size, void* d_ws, size_t ws_size,
                              hipStream_t stream) {
  const float* x = (const float*)d_in[0];
  const float *w1, *w2, *w3, *g1, *b1, *m1, *v1, *g2, *b2, *m2, *v2, *g3, *b3, *m3, *v3;
  if (in_sizes[2] == 9216) {
    w1 = (const float*)d_in[1];  w2 = (const float*)d_in[2];  w3 = (const float*)d_in[3];
    g1 = (const float*)d_in[4];  b1 = (const float*)d_in[5];  m1 = (const float*)d_in[6];  v1 = (const float*)d_in[7];
    g2 = (const float*)d_in[8];  b2 = (const float*)d_in[9];  m2 = (const float*)d_in[10]; v2 = (const float*)d_in[11];
    g3 = (const float*)d_in[12]; b3 = (const float*)d_in[13]; m3 = (const float*)d_in[14]; v3 = (const float*)d_in[15];
  } else {
    w1 = (const float*)d_in[1];  g1 = (const float*)d_in[2];  b1 = (const float*)d_in[3];  m1 = (const float*)d_in[4];  v1 = (const float*)d_in[5];
    w2 = (const float*)d_in[6];  g2 = (const float*)d_in[7];  b2 = (const float*)d_in[8];  m2 = (const float*)d_in[9];  v2 = (const float*)d_in[10];
    w3 = (const float*)d_in[11]; g3 = (const float*)d_in[12]; b3 = (const float*)d_in[13]; m3 = (const float*)d_in[14]; v3 = (const float*)d_in[15];
  }

  char* ws = (char*)d_ws;
  u16*   bufA = (u16*)ws;
  u16*   bufB = (u16*)(ws + 67108864);
  u16*   w1f  = (u16*)(ws + 134217728);
  u16*   w3f  = (u16*)(ws + 134217728 + 2097152);
  float* w2f  = (float*)(ws + 134217728 + 4194304);
  float* bs1  = (float*)(ws + 138448896);
  float* bs2  = (float*)(ws + 138452992);
  float* bs3  = (float*)(ws + 138457088);

  prep_kernel<<<2048, 256, 0, stream>>>(w1, w2, w3, g1, b1, m1, v1, g2, b2, m2, v2,
                                        g3, b3, m3, v3, w1f, w3f, w2f, bs1, bs2, bs3);
  pack_x<<<dim3(64, 16, 8), 256, 0, stream>>>(x, bufA);
  gemm_kernel<0><<<2048, 256, 0, stream>>>(bufA, w1f, bs1, nullptr, bufB);
  attn_kernel<<<8192, 256, 0, stream>>>(bufB, bufA);
  dwconv_kernel<<<8192, 256, 0, stream>>>(bufA, w2f, bs2, bufB);
  gemm_kernel<1><<<2048, 256, 0, stream>>>(bufB, w3f, bs3, x, d_out);
}